// Round 1
// baseline (231.367 us; speedup 1.0000x reference)
//
#include <hip/hip_runtime.h>
#include <hip/hip_fp16.h>

#define BB   128
#define NN   4096
#define OUTD 64
#define P1   64
#define P2   128
#define P3   256
#define R1   256
#define R2   128

#define CHUNK 64
#define H1S   72    // 64 + 8 pad (fp16), row stride 144 B (16B-aligned)
#define H2S   136   // 128 + 8 pad (fp16), row stride 272 B (16B-aligned)

typedef _Float16 half8 __attribute__((ext_vector_type(8)));
typedef float    f32x4 __attribute__((ext_vector_type(4)));

// workspace layout
#define AGG_OFF 0                        // 128*256 f32 = 131072 B
#define W2T_OFF (BB * P3 * 4)            // W2^T fp16 [128 ch][64 k]  = 16384 B
#define W3T_OFF (W2T_OFF + P2 * P1 * 2)  // W3^T fp16 [256 ch][128 k] = 65536 B

__global__ void prep_kernel(const float* __restrict__ w2, const float* __restrict__ w3,
                            unsigned char* ws) {
  int idx = blockIdx.x * 256 + threadIdx.x;
  _Float16* W2T = (_Float16*)(ws + W2T_OFF);
  _Float16* W3T = (_Float16*)(ws + W3T_OFF);
  if (idx < P1 * P2) {                       // 8192: w2 [64][128] -> W2T [128][64]
    int ch = idx >> 6, k = idx & 63;
    W2T[ch * P1 + k] = (_Float16)w2[k * P2 + ch];
  }
  int idx2 = idx - P1 * P2;
  if (idx2 >= 0 && idx2 < P2 * P3) {         // 32768: w3 [128][256] -> W3T [256][128]
    int ch = idx2 >> 7, k = idx2 & 127;
    W3T[ch * P2 + k] = (_Float16)w3[k * P3 + ch];
  }
}

// one block = one (batch, 64-point chunk). Early exit past lengths[b].
__launch_bounds__(256, 2)
__global__ void phi_kernel(const float* __restrict__ pts, const int* __restrict__ lengths,
                           const float* __restrict__ w1, const float* __restrict__ b1,
                           const float* __restrict__ b2, const float* __restrict__ b3,
                           unsigned char* ws) {
  __shared__ __align__(16) _Float16 sH1[CHUNK][H1S];      //  9216 B
  __shared__ __align__(16) _Float16 sW2T[P2][H1S];        // 18432 B
  __shared__ __align__(16) _Float16 sH2[CHUNK][H2S];      // 17408 B
  __shared__ __align__(16) _Float16 sW3T[2][64][H2S];     // 34816 B  (total 79872 -> 2 blk/CU)

  int b  = blockIdx.y;
  int c0 = blockIdx.x * CHUNK;
  int len = lengths[b];
  if (c0 >= len) return;                 // block-uniform: safe before barriers
  int v = min(CHUNK, len - c0);

  int t = threadIdx.x;
  int w = t >> 6, l = t & 63;
  int ml = l & 15, q = l >> 4;

  const uint4* W2Tg = (const uint4*)(ws + W2T_OFF);
  const uint4* W3Tg = (const uint4*)(ws + W3T_OFF);

  // stage W2T (16 KB) and W3T slab 0 (16 KB) into LDS
#pragma unroll
  for (int j = 0; j < 4; ++j) {
    int u = t + 256 * j;
    uint4 d = W2Tg[u];
    *(uint4*)&sW2T[u >> 3][(u & 7) * 8] = d;
  }
#pragma unroll
  for (int j = 0; j < 4; ++j) {
    int u = t + 256 * j;
    uint4 d = W3Tg[u];
    *(uint4*)&sW3T[0][u >> 4][(u & 15) * 8] = d;
  }

  // L1 (K=2) on VALU fp32, store h1 as fp16
  {
    const float* Pp = pts + ((size_t)b * NN + c0) * 2;
    int p = t >> 2, jg = (t & 3) * 16;
    float x = Pp[2 * p], y = Pp[2 * p + 1];
#pragma unroll
    for (int j = 0; j < 16; ++j) {
      int jj = jg + j;
      float h = fmaf(y, w1[P1 + jj], fmaf(x, w1[jj], b1[jj]));
      sH1[p][jj] = (_Float16)fmaxf(h, 0.f);
    }
  }
  __syncthreads();

  // L2: [64 pts x 64] x [64 x 128] -> h2. wave w owns ch [w*32, w*32+32)
  {
    f32x4 acc[4][2] = {};
#pragma unroll
    for (int ks = 0; ks < 2; ++ks) {
      int k0 = ks * 32 + q * 8;
      half8 a[4], bf[2];
#pragma unroll
      for (int mt = 0; mt < 4; ++mt) a[mt] = *(const half8*)&sH1[mt * 16 + ml][k0];
#pragma unroll
      for (int j = 0; j < 2; ++j)  bf[j] = *(const half8*)&sW2T[(2 * w + j) * 16 + ml][k0];
#pragma unroll
      for (int mt = 0; mt < 4; ++mt)
#pragma unroll
        for (int j = 0; j < 2; ++j)
          acc[mt][j] = __builtin_amdgcn_mfma_f32_16x16x32_f16(a[mt], bf[j], acc[mt][j], 0, 0, 0);
    }
#pragma unroll
    for (int j = 0; j < 2; ++j) {
      int ch = (2 * w + j) * 16 + ml;
      float bb = b2[ch];
#pragma unroll
      for (int mt = 0; mt < 4; ++mt)
#pragma unroll
        for (int r = 0; r < 4; ++r) {
          int p = mt * 16 + q * 4 + r;            // C/D: row = quad*4+reg, col = lane&15
          sH2[p][ch] = (_Float16)fmaxf(acc[mt][j][r] + bb, 0.f);
        }
    }
  }
  __syncthreads();

  unsigned* aggU = (unsigned*)(ws + AGG_OFF) + b * P3;

  // L3: [64 x 128] x [128 x 256] in 4 slabs of 64 ch, double-buffered LDS
  for (int s = 0; s < 4; ++s) {
    int buf = s & 1;
    bool more = (s + 1 < 4);
    uint4 pre[4];
    if (more) {
#pragma unroll
      for (int j = 0; j < 4; ++j) pre[j] = W3Tg[(s + 1) * 1024 + t + 256 * j];
    }
    int ch = s * 64 + w * 16 + ml;                // wave w owns one 16-ch tile per slab
    float bb = b3[ch];
    f32x4 acc[4] = {};
#pragma unroll
    for (int ks = 0; ks < 4; ++ks) {
      int k0 = ks * 32 + q * 8;
      half8 bf = *(const half8*)&sW3T[buf][w * 16 + ml][k0];
#pragma unroll
      for (int mt = 0; mt < 4; ++mt) {
        half8 a = *(const half8*)&sH2[mt * 16 + ml][k0];
        acc[mt] = __builtin_amdgcn_mfma_f32_16x16x32_f16(a, bf, acc[mt], 0, 0, 0);
      }
    }
    // bias + ReLU + validity mask + max over 16 local pts, then across quads
    float mx = 0.f;
#pragma unroll
    for (int mt = 0; mt < 4; ++mt)
#pragma unroll
      for (int r = 0; r < 4; ++r) {
        float val = fmaxf(acc[mt][r] + bb, 0.f);
        int p = mt * 16 + q * 4 + r;
        if (p >= v) val = 0.f;                    // invalid point -> 0 (max >= 0 always)
        mx = fmaxf(mx, val);
      }
    mx = fmaxf(mx, __shfl_xor(mx, 16));
    mx = fmaxf(mx, __shfl_xor(mx, 32));
    if (q == 0) atomicMax(&aggU[ch], __float_as_uint(mx));  // mx>=0: uint order == float order

    if (more) {
#pragma unroll
      for (int j = 0; j < 4; ++j) {
        int u = t + 256 * j;
        *(uint4*)&sW3T[buf ^ 1][u >> 4][(u & 15) * 8] = pre[j];
      }
    }
    __syncthreads();
  }
}

// rho MLP, fp32, one block per batch row
__global__ void rho_kernel(const unsigned char* __restrict__ ws,
                           const float* __restrict__ r1w, const float* __restrict__ r1b,
                           const float* __restrict__ r2w, const float* __restrict__ r2b,
                           const float* __restrict__ r3w, const float* __restrict__ r3b,
                           float* __restrict__ out) {
  __shared__ float sa[R1], sz1[R1], sz2[R2];
  int b = blockIdx.x, t = threadIdx.x;
  const float* agg = (const float*)(ws + AGG_OFF) + b * P3;
  sa[t] = agg[t];
  __syncthreads();
  float a1 = r1b[t];
#pragma unroll 8
  for (int k = 0; k < P3; ++k) a1 = fmaf(sa[k], r1w[k * R1 + t], a1);
  sz1[t] = fmaxf(a1, 0.f);
  __syncthreads();
  if (t < R2) {
    float a2 = r2b[t];
#pragma unroll 8
    for (int k = 0; k < R1; ++k) a2 = fmaf(sz1[k], r2w[k * R2 + t], a2);
    sz2[t] = fmaxf(a2, 0.f);
  }
  __syncthreads();
  if (t < OUTD) {
    float a3 = r3b[t];
#pragma unroll 8
    for (int k = 0; k < R2; ++k) a3 = fmaf(sz2[k], r3w[k * OUTD + t], a3);
    out[b * OUTD + t] = a3;
  }
}

extern "C" void kernel_launch(void* const* d_in, const int* in_sizes, int n_in,
                              void* d_out, int out_size, void* d_ws, size_t ws_size,
                              hipStream_t stream) {
  const float* pts     = (const float*)d_in[0];
  const int*   lengths = (const int*)d_in[1];
  const float* w1  = (const float*)d_in[2];
  const float* b1  = (const float*)d_in[3];
  const float* w2  = (const float*)d_in[4];
  const float* b2  = (const float*)d_in[5];
  const float* w3  = (const float*)d_in[6];
  const float* b3  = (const float*)d_in[7];
  const float* r1w = (const float*)d_in[8];
  const float* r1b = (const float*)d_in[9];
  const float* r2w = (const float*)d_in[10];
  const float* r2b = (const float*)d_in[11];
  const float* r3w = (const float*)d_in[12];
  const float* r3b = (const float*)d_in[13];
  unsigned char* ws = (unsigned char*)d_ws;

  hipMemsetAsync(ws + AGG_OFF, 0, BB * P3 * 4, stream);   // agg = 0 (valid: all h3 >= 0)
  prep_kernel<<<160, 256, 0, stream>>>(w2, w3, ws);
  phi_kernel<<<dim3(NN / CHUNK, BB), 256, 0, stream>>>(pts, lengths, w1, b1, b2, b3, ws);
  rho_kernel<<<BB, 256, 0, stream>>>(ws, r1w, r1b, r2w, r2b, r3w, r3b, (float*)d_out);
}